// Round 1
// baseline (189.789 us; speedup 1.0000x reference)
//
#include <hip/hip_runtime.h>

// Problem dims (hard-coded in reference)
#define DD   768
#define NN   512
#define MM   512

// ---- fast-math helpers -----------------------------------------------------
#if defined(__has_builtin)
  #if __has_builtin(__builtin_amdgcn_exp2f)
    #define HAVE_EXP2 1
  #endif
  #if __has_builtin(__builtin_amdgcn_rcpf)
    #define HAVE_RCP 1
  #endif
#endif

#ifdef HAVE_EXP2
  // fexp(x) computes 2^x; caller pre-scales by 2*log2(e) so fexp(PRE_K*v) = e^{2v}
  __device__ __forceinline__ float fexp(float x) { return __builtin_amdgcn_exp2f(x); }
  #define PRE_K 2.88539008177792681472f   // 2*log2(e)
#else
  __device__ __forceinline__ float fexp(float x) { return __expf(x); }
  #define PRE_K 2.0f
#endif

__device__ __forceinline__ float frcp(float x) {
#ifdef HAVE_RCP
  return __builtin_amdgcn_rcpf(x);
#else
  return 1.0f / x;
#endif
}

// tanh(x) = 1 - 2/(1 + e^{2x}); saturates correctly via exp2->inf/0 + rcp.
__device__ __forceinline__ float fast_tanh(float x) {
  float e = fexp(PRE_K * x);
  return 1.0f - 2.0f * frcp(e + 1.0f);
}

// ---- generic 64x64 fp32 GEMM tile (256 thr, 4x4 per thread, BK=16) ---------
// Out[i,j] = scale * sum_k X[i,k] * (transB ? W[j,k] : W[k,j])
__device__ __forceinline__ void gemm_tile(
    const float* __restrict__ X, const float* __restrict__ W,
    float* __restrict__ Out, int ldo,
    int i0, int j0, int ldx, int ldw,
    int k0, int k1, bool transB, float scale)
{
  __shared__ float Xs[16][64];   // [k][row]
  __shared__ float Ws[16][64];   // [k][col]
  const int tid = threadIdx.x;
  const int tx = tid & 15;       // col group
  const int ty = tid >> 4;       // row group
  float acc[4][4] = {};

  for (int k = k0; k < k1; k += 16) {
    // stage X tile (64 rows x 16 k), one float4 per thread, store transposed
    {
      const int row = tid >> 2;
      const int kq  = (tid & 3) << 2;
      const float4 v = *(const float4*)&X[(i0 + row) * ldx + k + kq];
      Xs[kq + 0][row] = v.x; Xs[kq + 1][row] = v.y;
      Xs[kq + 2][row] = v.z; Xs[kq + 3][row] = v.w;
    }
    if (!transB) {
      const int r  = tid >> 4;           // k index 0..15
      const int cq = (tid & 15) << 2;    // col 0..63 step 4
      *(float4*)&Ws[r][cq] = *(const float4*)&W[(k + r) * ldw + j0 + cq];
    } else {
      const int c  = tid >> 2;           // col 0..63
      const int kq = (tid & 3) << 2;
      const float4 v = *(const float4*)&W[(j0 + c) * ldw + k + kq];
      Ws[kq + 0][c] = v.x; Ws[kq + 1][c] = v.y;
      Ws[kq + 2][c] = v.z; Ws[kq + 3][c] = v.w;
    }
    __syncthreads();
    #pragma unroll
    for (int kk = 0; kk < 16; ++kk) {
      const float4 xv = *(const float4*)&Xs[kk][ty << 2];
      const float4 wv = *(const float4*)&Ws[kk][tx << 2];
      const float xa[4] = {xv.x, xv.y, xv.z, xv.w};
      const float wa[4] = {wv.x, wv.y, wv.z, wv.w};
      #pragma unroll
      for (int r = 0; r < 4; ++r)
        #pragma unroll
        for (int c = 0; c < 4; ++c)
          acc[r][c] = fmaf(xa[r], wa[c], acc[r][c]);
    }
    __syncthreads();
  }

  #pragma unroll
  for (int r = 0; r < 4; ++r) {
    float4 o;
    o.x = acc[r][0] * scale; o.y = acc[r][1] * scale;
    o.z = acc[r][2] * scale; o.w = acc[r][3] * scale;
    *(float4*)&Out[(i0 + (ty << 2) + r) * ldo + j0 + (tx << 2)] = o;
  }
}

// z=0: A = text@W1 ; z=1: kw2t = PRE_K*(text@W2) ; z=2: kw3v = PRE_K*(visual@W3^T)
__global__ __launch_bounds__(256) void gemm3_kernel(
    const float* __restrict__ text, const float* __restrict__ visual,
    const float* __restrict__ W1, const float* __restrict__ W2,
    const float* __restrict__ W3,
    float* __restrict__ A, float* __restrict__ kw2t, float* __restrict__ kw3v)
{
  const int i0 = blockIdx.y * 64;
  const int j0 = blockIdx.x * 64;
  const int z  = blockIdx.z;
  if (z == 0)
    gemm_tile(text,   W1, A,    DD, i0, j0, DD, DD, 0, DD, false, 1.0f);
  else if (z == 1)
    gemm_tile(text,   W2, kw2t, DD, i0, j0, DD, DD, 0, DD, false, PRE_K);
  else
    gemm_tile(visual, W3, kw3v, DD, i0, j0, DD, DD, 0, DD, true,  PRE_K);
}

// Craw = A @ visual^T, K split in 2 (z) into C0/C1 for more blocks in flight
__global__ __launch_bounds__(256) void cgemm_kernel(
    const float* __restrict__ A, const float* __restrict__ visual,
    float* __restrict__ C0, float* __restrict__ C1)
{
  const int i0 = blockIdx.y * 64;
  const int j0 = blockIdx.x * 64;
  float* Out = blockIdx.z ? C1 : C0;
  gemm_tile(A, visual, Out, MM, i0, j0, DD, DD,
            blockIdx.z * (DD / 2), (blockIdx.z + 1) * (DD / 2), true, 1.0f);
}

// T[n] = sum_d text[n,d]  (for score = T[n] - 2*sum text*r identity)
__global__ __launch_bounds__(64) void tsum_kernel(
    const float* __restrict__ text, float* __restrict__ T)
{
  const int n = blockIdx.x;
  const int lane = threadIdx.x;
  float s = 0.f;
  #pragma unroll
  for (int i = 0; i < DD / 64; ++i) s += text[n * DD + lane + i * 64];
  #pragma unroll
  for (int off = 32; off; off >>= 1) s += __shfl_down(s, off);
  if (lane == 0) T[n] = s;
}

// ---- main fused kernel -----------------------------------------------------
// score[n,m] = T[n] - 2 * sum_d text[n,d] * rcp(1 + exp2(kw2t[n,d] + kw3v[m,d]*C[n,m]))
#define DCH 128          // d-chunk staged per iteration
#define LDW 132          // LDS row stride (pad 128 -> 132: float4-aligned, 2-way max)

__global__ __launch_bounds__(256) void main_kernel(
    const float* __restrict__ text, const float* __restrict__ kw2t,
    const float* __restrict__ kw3v, const float* __restrict__ C0,
    const float* __restrict__ C1,   const float* __restrict__ T,
    float* __restrict__ out)
{
  __shared__ float ts[16][LDW];
  __shared__ float w2s[16][LDW];
  __shared__ float w3s[16][LDW];

  const int tid = threadIdx.x;
  const int nl = tid >> 4;            // local n 0..15
  const int ml = tid & 15;            // local m 0..15
  const int n0 = blockIdx.y * 16;
  const int m0 = blockIdx.x * 16;
  const int n = n0 + nl, m = m0 + ml;

  const float craw = C0[n * MM + m] + C1[n * MM + m];
  const float cval = fast_tanh(craw);

  float a0 = 0.f, a1 = 0.f, a2 = 0.f, a3 = 0.f;

  for (int d0 = 0; d0 < DD; d0 += DCH) {
    #pragma unroll
    for (int t = 0; t < 2; ++t) {
      const int q   = tid + t * 256;      // 0..511 (16 rows x 32 float4)
      const int row = q >> 5;
      const int c4  = (q & 31) << 2;
      const float4 tv = *(const float4*)&text[(n0 + row) * DD + d0 + c4];
      const float4 av = *(const float4*)&kw2t[(n0 + row) * DD + d0 + c4];
      const float4 bv = *(const float4*)&kw3v[(m0 + row) * DD + d0 + c4];
      *(float4*)&ts[row][c4]  = tv;
      *(float4*)&w2s[row][c4] = av;
      *(float4*)&w3s[row][c4] = bv;
    }
    __syncthreads();

    #pragma unroll 4
    for (int j = 0; j < DCH; j += 4) {
      const float4 tv = *(const float4*)&ts[nl][j];
      const float4 w2 = *(const float4*)&w2s[nl][j];
      const float4 w3 = *(const float4*)&w3s[ml][j];
      const float p0 = fmaf(w3.x, cval, w2.x);
      const float p1 = fmaf(w3.y, cval, w2.y);
      const float p2 = fmaf(w3.z, cval, w2.z);
      const float p3 = fmaf(w3.w, cval, w2.w);
      a0 = fmaf(tv.x, frcp(fexp(p0) + 1.0f), a0);
      a1 = fmaf(tv.y, frcp(fexp(p1) + 1.0f), a1);
      a2 = fmaf(tv.z, frcp(fexp(p2) + 1.0f), a2);
      a3 = fmaf(tv.w, frcp(fexp(p3) + 1.0f), a3);
    }
    __syncthreads();
  }

  const float acc = (a0 + a1) + (a2 + a3);
  out[n * MM + m] = T[n] - 2.0f * acc;
}

// ---- launcher --------------------------------------------------------------
extern "C" void kernel_launch(void* const* d_in, const int* in_sizes, int n_in,
                              void* d_out, int out_size, void* d_ws, size_t ws_size,
                              hipStream_t stream) {
  const float* text   = (const float*)d_in[0];
  const float* visual = (const float*)d_in[1];
  const float* W1     = (const float*)d_in[2];
  const float* W2     = (const float*)d_in[3];
  const float* W3     = (const float*)d_in[4];
  float* out = (float*)d_out;

  float* ws   = (float*)d_ws;
  float* A    = ws;                         // 512*768
  float* kw2t = ws + NN * DD;               // 512*768
  float* kw3v = ws + 2 * NN * DD;           // 512*768
  float* C0   = ws + 3 * NN * DD;           // 512*512
  float* C1   = C0 + NN * MM;               // 512*512
  float* T    = C1 + NN * MM;               // 512

  hipLaunchKernelGGL(tsum_kernel, dim3(NN), dim3(64), 0, stream, text, T);
  hipLaunchKernelGGL(gemm3_kernel, dim3(DD / 64, NN / 64, 3), dim3(256), 0, stream,
                     text, visual, W1, W2, W3, A, kw2t, kw3v);
  hipLaunchKernelGGL(cgemm_kernel, dim3(MM / 64, NN / 64, 2), dim3(256), 0, stream,
                     A, visual, C0, C1);
  hipLaunchKernelGGL(main_kernel, dim3(MM / 16, NN / 16), dim3(256), 0, stream,
                     text, kw2t, kw3v, C0, C1, T, out);
}